// Round 7
// baseline (89.054 us; speedup 1.0000x reference)
//
#include <hip/hip_runtime.h>
#include <math.h>

#define NTOK 4096
#define NDIM 1024
#define KTOT 2048
#define NEXP 64
#define MT   64          // tokens per block tile
#define KB   64          // fp32 k per LDS stage
#define LSTR 72          // fp16 row stride in LDS (144 B)
#define NKC  16          // split-K factor
#define NSTG 2           // stages per chunk: (2048/16)/64

typedef _Float16 half8 __attribute__((ext_vector_type(8)));
typedef _Float16 half4 __attribute__((ext_vector_type(4)));
typedef float    floatx4 __attribute__((ext_vector_type(4)));

#define XSCALE 16.0f
#define WSCALE 1024.0f
#define INVSCALE (1.0f / (16.0f * 1024.0f))

struct h2pair { _Float16 h, l; };
__device__ __forceinline__ h2pair split2(float v) {
    h2pair r;
    r.h = (_Float16)v;
    r.l = (_Float16)(v - (float)r.h);
    return r;
}

// ---------------------------------------------------------------------------
// Split-K MFMA GEMM (round-5 proven structure, no software pipeline).
// Block = 64 tokens x 64 experts, 4 waves, 4 blocks/CU.
// fp32 tiles -> fp16 (hi,lo) pairs in LDS; 3-pass mfma: xh*wh + xl*wh + xh*wl.
// Norm partials folded into staging. grid = (NTOK/MT, NKC), block = 256.
// ---------------------------------------------------------------------------
__global__ __launch_bounds__(256, 4) void gemm_mfma(const float* __restrict__ t1,
                                                    const float* __restrict__ t2,
                                                    const float* __restrict__ W,
                                                    float* __restrict__ Gp,
                                                    float* __restrict__ Cp,
                                                    float* __restrict__ Wp) {
    __shared__ _Float16 Xh[MT * LSTR], Xl[MT * LSTR];
    __shared__ _Float16 Wh[NEXP * LSTR], Wl[NEXP * LSTR];

    const int tid  = threadIdx.x;
    const int lane = tid & 63;
    const int wv   = tid >> 6;          // wave id: token strip 16*wv..16*wv+15
    const int srow = tid >> 4;          // staging row 0..15
    const int scol = tid & 15;          // staging float4 col 0..15
    const int kc   = blockIdx.y;
    const int kbase = kc * (NSTG * KB);
    const int tok0  = blockIdx.x * MT;

    const float* __restrict__ xsrc = (kbase < NDIM)
        ? (t1 + (size_t)tok0 * NDIM + kbase)
        : (t2 + (size_t)tok0 * NDIM + (kbase - NDIM));
    const float* __restrict__ wsrc = W + kbase;

    floatx4 acc[4];
    #pragma unroll
    for (int j = 0; j < 4; ++j) { acc[j][0] = 0.f; acc[j][1] = 0.f; acc[j][2] = 0.f; acc[j][3] = 0.f; }
    float ssx[4] = {0.f, 0.f, 0.f, 0.f};
    float ssw[4] = {0.f, 0.f, 0.f, 0.f};

    const int frow = lane & 15;
    const int fq   = lane >> 4;
    const _Float16* xh_p = Xh + (16 * wv + frow) * LSTR + fq * 8;
    const _Float16* xl_p = Xl + (16 * wv + frow) * LSTR + fq * 8;

    #pragma unroll
    for (int s = 0; s < NSTG; ++s) {
        // ---- stage: load fp32, split to fp16 hi/lo, write LDS ----
        #pragma unroll
        for (int i = 0; i < 4; ++i) {
            const int row = srow + 16 * i;
            const float4 xv = *reinterpret_cast<const float4*>(
                xsrc + (size_t)row * NDIM + s * KB + scol * 4);
            const float4 wq = *reinterpret_cast<const float4*>(
                wsrc + (size_t)row * KTOT + s * KB + scol * 4);
            ssx[i] = fmaf(xv.x, xv.x, fmaf(xv.y, xv.y, fmaf(xv.z, xv.z, fmaf(xv.w, xv.w, ssx[i]))));
            ssw[i] = fmaf(wq.x, wq.x, fmaf(wq.y, wq.y, fmaf(wq.z, wq.z, fmaf(wq.w, wq.w, ssw[i]))));
            const h2pair x0 = split2(xv.x * XSCALE), x1 = split2(xv.y * XSCALE);
            const h2pair x2 = split2(xv.z * XSCALE), x3 = split2(xv.w * XSCALE);
            const h2pair w0 = split2(wq.x * WSCALE), w1 = split2(wq.y * WSCALE);
            const h2pair w2 = split2(wq.z * WSCALE), w3 = split2(wq.w * WSCALE);
            half4 hx, lx, hw, lw;
            hx[0] = x0.h; hx[1] = x1.h; hx[2] = x2.h; hx[3] = x3.h;
            lx[0] = x0.l; lx[1] = x1.l; lx[2] = x2.l; lx[3] = x3.l;
            hw[0] = w0.h; hw[1] = w1.h; hw[2] = w2.h; hw[3] = w3.h;
            lw[0] = w0.l; lw[1] = w1.l; lw[2] = w2.l; lw[3] = w3.l;
            *reinterpret_cast<half4*>(Xh + row * LSTR + scol * 4) = hx;
            *reinterpret_cast<half4*>(Xl + row * LSTR + scol * 4) = lx;
            *reinterpret_cast<half4*>(Wh + row * LSTR + scol * 4) = hw;
            *reinterpret_cast<half4*>(Wl + row * LSTR + scol * 4) = lw;
        }
        __syncthreads();

        // ---- compute: 2 K-steps of 32, 3 passes (hh, lh, hl) ----
        #pragma unroll
        for (int ks = 0; ks < 2; ++ks) {
            const int ko = ks * 32;
            const half8 ah = *reinterpret_cast<const half8*>(xh_p + ko);
            const half8 al = *reinterpret_cast<const half8*>(xl_p + ko);
            half8 bh[4], bl[4];
            #pragma unroll
            for (int j = 0; j < 4; ++j) {
                bh[j] = *reinterpret_cast<const half8*>(Wh + (16 * j + frow) * LSTR + fq * 8 + ko);
                bl[j] = *reinterpret_cast<const half8*>(Wl + (16 * j + frow) * LSTR + fq * 8 + ko);
            }
            #pragma unroll
            for (int j = 0; j < 4; ++j)
                acc[j] = __builtin_amdgcn_mfma_f32_16x16x32_f16(ah, bh[j], acc[j], 0, 0, 0);
            #pragma unroll
            for (int j = 0; j < 4; ++j)
                acc[j] = __builtin_amdgcn_mfma_f32_16x16x32_f16(al, bh[j], acc[j], 0, 0, 0);
            #pragma unroll
            for (int j = 0; j < 4; ++j)
                acc[j] = __builtin_amdgcn_mfma_f32_16x16x32_f16(ah, bl[j], acc[j], 0, 0, 0);
        }
        __syncthreads();
    }

    // ---- write dot partials (C/D layout: col=lane&15, row=(lane>>4)*4+reg) ----
    const int m0 = 16 * wv + fq * 4;
    #pragma unroll
    for (int j = 0; j < 4; ++j) {
        #pragma unroll
        for (int i = 0; i < 4; ++i) {
            Gp[((size_t)kc * NTOK + tok0 + m0 + i) * NEXP + 16 * j + frow] = acc[j][i] * INVSCALE;
        }
    }

    // ---- norm partials: reduce across the 16 staging lanes of each row ----
    #pragma unroll
    for (int off = 1; off < 16; off <<= 1) {
        #pragma unroll
        for (int i = 0; i < 4; ++i) {
            ssx[i] += __shfl_xor(ssx[i], off, 64);
            ssw[i] += __shfl_xor(ssw[i], off, 64);
        }
    }
    if (scol == 0) {
        #pragma unroll
        for (int i = 0; i < 4; ++i)
            Cp[(size_t)kc * NTOK + tok0 + srow + 16 * i] = ssx[i];
        if (blockIdx.x == 0) {
            #pragma unroll
            for (int i = 0; i < 4; ++i)
                Wp[kc * NEXP + srow + 16 * i] = ssw[i];
        }
    }
}

// ---------------------------------------------------------------------------
// Finalize: one wave per token, lane = expert.  Compile-time NKC unroll so
// all partial loads issue back-to-back (one memory latency).
// ---------------------------------------------------------------------------
__global__ __launch_bounds__(256) void finalize(const float* __restrict__ Gp,
                                                const float* __restrict__ Cp,
                                                const float* __restrict__ Wp,
                                                float* __restrict__ out) {
    const int wv = threadIdx.x >> 6, lane = threadIdx.x & 63;
    const int token = blockIdx.x * 4 + wv;

    float gsum = 0.f, csum = 0.f, nv = 0.f;
    #pragma unroll
    for (int cix = 0; cix < NKC; ++cix) {
        gsum += Gp[((size_t)cix * NTOK + token) * NEXP + lane];
        csum += Cp[(size_t)cix * NTOK + token];
        nv   += Wp[cix * NEXP + lane];
    }

    const float S = fmaf(-2.f, gsum, csum) + nv;
    const float logit = -sqrtf(S);

    float v1 = logit; int i1 = lane;
    #pragma unroll
    for (int off = 32; off > 0; off >>= 1) {
        float ov = __shfl_xor(v1, off, 64);
        int   oi = __shfl_xor(i1, off, 64);
        if (ov > v1 || (ov == v1 && oi < i1)) { v1 = ov; i1 = oi; }
    }
    float v2 = (lane == i1) ? -__builtin_inff() : logit;
    int   i2 = lane;
    #pragma unroll
    for (int off = 32; off > 0; off >>= 1) {
        float ov = __shfl_xor(v2, off, 64);
        int   oi = __shfl_xor(i2, off, 64);
        if (ov > v2 || (ov == v2 && oi < i2)) { v2 = ov; i2 = oi; }
    }
    const float e2  = expf(v2 - v1);
    const float inv = 1.f / (1.f + e2);
    const float o = (lane == i1) ? inv : ((lane == i2) ? e2 * inv : 0.f);
    out[(size_t)token * NEXP + lane] = o;
}

// ---------------------------------------------------------------------------
extern "C" void kernel_launch(void* const* d_in, const int* in_sizes, int n_in,
                              void* d_out, int out_size, void* d_ws, size_t ws_size,
                              hipStream_t stream) {
    const float* t1 = (const float*)d_in[0];
    const float* t2 = (const float*)d_in[1];
    const float* W  = (const float*)d_in[2];
    float* out = (float*)d_out;

    float* Gp = (float*)d_ws;                        // NKC*NTOK*NEXP floats (16 MB)
    float* Cp = Gp + (size_t)NKC * NTOK * NEXP;      // NKC*NTOK
    float* Wp = Cp + (size_t)NKC * NTOK;             // NKC*NEXP

    gemm_mfma<<<dim3(NTOK / MT, NKC), 256, 0, stream>>>(t1, t2, W, Gp, Cp, Wp);
    finalize<<<NTOK / 4, 256, 0, stream>>>(Gp, Cp, Wp, out);
}

// Round 8
// 88.980 us; speedup vs baseline: 1.0008x; 1.0008x over previous
//
#include <hip/hip_runtime.h>
#include <math.h>

#define NTOK 4096
#define NDIM 1024
#define KTOT 2048
#define NEXP 64
#define MT   64          // tokens per block tile
#define KB   64          // k per LDS stage
#define LSTR 72          // fp16 row stride in LDS (144 B)
#define NKC  8           // split-K factor
#define NSTG 4           // stages per chunk: (2048/8)/64

typedef _Float16 half8 __attribute__((ext_vector_type(8)));
typedef _Float16 half4 __attribute__((ext_vector_type(4)));
typedef float    floatx4 __attribute__((ext_vector_type(4)));

#define XSCALE 16.0f
#define WSCALE 1024.0f
#define INVSCALE (1.0f / (16.0f * 1024.0f))

struct h2pair { _Float16 h, l; };
__device__ __forceinline__ h2pair split2(float v) {
    h2pair r;
    r.h = (_Float16)v;
    r.l = (_Float16)(v - (float)r.h);
    return r;
}

// ---------------------------------------------------------------------------
// prep_w: convert W (fp32) -> scaled fp16 hi/lo planes (once, not per block),
// and compute full ||w_e||^2.  grid = 64 blocks x 256 threads; thread t owns
// 8 consecutive floats of row e.
// ---------------------------------------------------------------------------
__global__ __launch_bounds__(256) void prep_w(const float* __restrict__ W,
                                              _Float16* __restrict__ Whg,
                                              _Float16* __restrict__ Wlg,
                                              float* __restrict__ nrm) {
    const int e = blockIdx.x, t = threadIdx.x;
    const float* row = W + (size_t)e * KTOT + t * 8;
    const float4 a = *reinterpret_cast<const float4*>(row);
    const float4 b = *reinterpret_cast<const float4*>(row + 4);
    float ss = fmaf(a.x, a.x, fmaf(a.y, a.y, fmaf(a.z, a.z, fmaf(a.w, a.w, 0.f))));
    ss = fmaf(b.x, b.x, fmaf(b.y, b.y, fmaf(b.z, b.z, fmaf(b.w, b.w, ss))));

    const h2pair p0 = split2(a.x * WSCALE), p1 = split2(a.y * WSCALE);
    const h2pair p2 = split2(a.z * WSCALE), p3 = split2(a.w * WSCALE);
    const h2pair p4 = split2(b.x * WSCALE), p5 = split2(b.y * WSCALE);
    const h2pair p6 = split2(b.z * WSCALE), p7 = split2(b.w * WSCALE);
    half8 h, l;
    h[0]=p0.h; h[1]=p1.h; h[2]=p2.h; h[3]=p3.h; h[4]=p4.h; h[5]=p5.h; h[6]=p6.h; h[7]=p7.h;
    l[0]=p0.l; l[1]=p1.l; l[2]=p2.l; l[3]=p3.l; l[4]=p4.l; l[5]=p5.l; l[6]=p6.l; l[7]=p7.l;
    *reinterpret_cast<half8*>(Whg + (size_t)e * KTOT + t * 8) = h;
    *reinterpret_cast<half8*>(Wlg + (size_t)e * KTOT + t * 8) = l;

    #pragma unroll
    for (int off = 32; off > 0; off >>= 1) ss += __shfl_down(ss, off, 64);
    __shared__ float red[4];
    const int lane = t & 63, wv = t >> 6;
    if (lane == 0) red[wv] = ss;
    __syncthreads();
    if (t == 0) nrm[e] = (red[0] + red[1]) + (red[2] + red[3]);
}

// ---------------------------------------------------------------------------
// Split-K MFMA GEMM (deterministic 2-barrier structure).  Block = 64 tokens x
// 64 experts, 4 waves.  X: fp32 load -> split fp16 hi/lo + norm partial.
// W: pre-converted fp16 planes, staged as pure b128 copies (no VALU).
// 3-pass mfma: xh*wh + xl*wh + xh*wl.  grid = (NTOK/MT, NKC), block = 256.
// ---------------------------------------------------------------------------
__global__ __launch_bounds__(256, 3) void gemm_mfma(const float* __restrict__ t1,
                                                    const float* __restrict__ t2,
                                                    const _Float16* __restrict__ Whg,
                                                    const _Float16* __restrict__ Wlg,
                                                    float* __restrict__ Gp,
                                                    float* __restrict__ Cp) {
    __shared__ _Float16 Xh[MT * LSTR], Xl[MT * LSTR];
    __shared__ _Float16 Wh[NEXP * LSTR], Wl[NEXP * LSTR];

    const int tid  = threadIdx.x;
    const int lane = tid & 63;
    const int wv   = tid >> 6;          // wave id: token strip 16*wv..16*wv+15
    const int srow = tid >> 4;          // X staging row 0..15
    const int scol = tid & 15;          // X staging float4 col 0..15
    const int wrow = tid >> 2;          // W staging row 0..63
    const int wseg = tid & 3;           // W staging 16-half segment 0..3
    const int kc   = blockIdx.y;
    const int kbase = kc * (NSTG * KB);
    const int tok0  = blockIdx.x * MT;

    const float* __restrict__ xsrc = (kbase < NDIM)
        ? (t1 + (size_t)tok0 * NDIM + kbase)
        : (t2 + (size_t)tok0 * NDIM + (kbase - NDIM));
    const _Float16* __restrict__ whsrc = Whg + (size_t)wrow * KTOT + kbase + wseg * 16;
    const _Float16* __restrict__ wlsrc = Wlg + (size_t)wrow * KTOT + kbase + wseg * 16;
    _Float16* whdst = Wh + wrow * LSTR + wseg * 16;
    _Float16* wldst = Wl + wrow * LSTR + wseg * 16;

    floatx4 acc[4];
    #pragma unroll
    for (int j = 0; j < 4; ++j) { acc[j][0] = 0.f; acc[j][1] = 0.f; acc[j][2] = 0.f; acc[j][3] = 0.f; }
    float ssx[4] = {0.f, 0.f, 0.f, 0.f};

    const int frow = lane & 15;
    const int fq   = lane >> 4;
    const _Float16* xh_p = Xh + (16 * wv + frow) * LSTR + fq * 8;
    const _Float16* xl_p = Xl + (16 * wv + frow) * LSTR + fq * 8;

    #pragma unroll
    for (int s = 0; s < NSTG; ++s) {
        // ---- stage W: pure fp16 b128 copies ----
        {
            const half8 wh0 = *reinterpret_cast<const half8*>(whsrc + s * KB);
            const half8 wh1 = *reinterpret_cast<const half8*>(whsrc + s * KB + 8);
            const half8 wl0 = *reinterpret_cast<const half8*>(wlsrc + s * KB);
            const half8 wl1 = *reinterpret_cast<const half8*>(wlsrc + s * KB + 8);
            *reinterpret_cast<half8*>(whdst)     = wh0;
            *reinterpret_cast<half8*>(whdst + 8) = wh1;
            *reinterpret_cast<half8*>(wldst)     = wl0;
            *reinterpret_cast<half8*>(wldst + 8) = wl1;
        }
        // ---- stage X: fp32 load, split, norm partial ----
        #pragma unroll
        for (int i = 0; i < 4; ++i) {
            const int row = srow + 16 * i;
            const float4 xv = *reinterpret_cast<const float4*>(
                xsrc + (size_t)row * NDIM + s * KB + scol * 4);
            ssx[i] = fmaf(xv.x, xv.x, fmaf(xv.y, xv.y, fmaf(xv.z, xv.z, fmaf(xv.w, xv.w, ssx[i]))));
            const h2pair x0 = split2(xv.x * XSCALE), x1 = split2(xv.y * XSCALE);
            const h2pair x2 = split2(xv.z * XSCALE), x3 = split2(xv.w * XSCALE);
            half4 hx, lx;
            hx[0] = x0.h; hx[1] = x1.h; hx[2] = x2.h; hx[3] = x3.h;
            lx[0] = x0.l; lx[1] = x1.l; lx[2] = x2.l; lx[3] = x3.l;
            *reinterpret_cast<half4*>(Xh + row * LSTR + scol * 4) = hx;
            *reinterpret_cast<half4*>(Xl + row * LSTR + scol * 4) = lx;
        }
        __syncthreads();

        // ---- compute: 2 K-steps of 32, 3 passes (hh, lh, hl) ----
        #pragma unroll
        for (int ks = 0; ks < 2; ++ks) {
            const int ko = ks * 32;
            const half8 ah = *reinterpret_cast<const half8*>(xh_p + ko);
            const half8 al = *reinterpret_cast<const half8*>(xl_p + ko);
            half8 bh[4], bl[4];
            #pragma unroll
            for (int j = 0; j < 4; ++j) {
                bh[j] = *reinterpret_cast<const half8*>(Wh + (16 * j + frow) * LSTR + fq * 8 + ko);
                bl[j] = *reinterpret_cast<const half8*>(Wl + (16 * j + frow) * LSTR + fq * 8 + ko);
            }
            #pragma unroll
            for (int j = 0; j < 4; ++j)
                acc[j] = __builtin_amdgcn_mfma_f32_16x16x32_f16(ah, bh[j], acc[j], 0, 0, 0);
            #pragma unroll
            for (int j = 0; j < 4; ++j)
                acc[j] = __builtin_amdgcn_mfma_f32_16x16x32_f16(al, bh[j], acc[j], 0, 0, 0);
            #pragma unroll
            for (int j = 0; j < 4; ++j)
                acc[j] = __builtin_amdgcn_mfma_f32_16x16x32_f16(ah, bl[j], acc[j], 0, 0, 0);
        }
        __syncthreads();
    }

    // ---- write dot partials (C/D layout: col=lane&15, row=(lane>>4)*4+reg) ----
    const int m0 = 16 * wv + fq * 4;
    #pragma unroll
    for (int j = 0; j < 4; ++j) {
        #pragma unroll
        for (int i = 0; i < 4; ++i) {
            Gp[((size_t)kc * NTOK + tok0 + m0 + i) * NEXP + 16 * j + frow] = acc[j][i];
        }
    }

    // ---- X norm partials: reduce across the 16 staging lanes of each row ----
    #pragma unroll
    for (int off = 1; off < 16; off <<= 1) {
        #pragma unroll
        for (int i = 0; i < 4; ++i) ssx[i] += __shfl_xor(ssx[i], off, 64);
    }
    if (scol == 0) {
        #pragma unroll
        for (int i = 0; i < 4; ++i)
            Cp[(size_t)kc * NTOK + tok0 + srow + 16 * i] = ssx[i];
    }
}

// ---------------------------------------------------------------------------
// Finalize: one wave per token, lane = expert.  Compile-time NKC unroll so
// all partial loads issue back-to-back (one memory latency).
// ---------------------------------------------------------------------------
__global__ __launch_bounds__(256) void finalize(const float* __restrict__ Gp,
                                                const float* __restrict__ Cp,
                                                const float* __restrict__ nrm,
                                                float* __restrict__ out) {
    const int wv = threadIdx.x >> 6, lane = threadIdx.x & 63;
    const int token = blockIdx.x * 4 + wv;

    float gsum = 0.f, csum = 0.f;
    #pragma unroll
    for (int cix = 0; cix < NKC; ++cix) {
        gsum += Gp[((size_t)cix * NTOK + token) * NEXP + lane];
        csum += Cp[(size_t)cix * NTOK + token];
    }
    const float nv = nrm[lane];

    const float S = fmaf(-2.f * INVSCALE, gsum, csum) + nv;
    const float logit = -sqrtf(S);

    float v1 = logit; int i1 = lane;
    #pragma unroll
    for (int off = 32; off > 0; off >>= 1) {
        float ov = __shfl_xor(v1, off, 64);
        int   oi = __shfl_xor(i1, off, 64);
        if (ov > v1 || (ov == v1 && oi < i1)) { v1 = ov; i1 = oi; }
    }
    float v2 = (lane == i1) ? -__builtin_inff() : logit;
    int   i2 = lane;
    #pragma unroll
    for (int off = 32; off > 0; off >>= 1) {
        float ov = __shfl_xor(v2, off, 64);
        int   oi = __shfl_xor(i2, off, 64);
        if (ov > v2 || (ov == v2 && oi < i2)) { v2 = ov; i2 = oi; }
    }
    const float e2  = expf(v2 - v1);
    const float inv = 1.f / (1.f + e2);
    const float o = (lane == i1) ? inv : ((lane == i2) ? e2 * inv : 0.f);
    out[(size_t)token * NEXP + lane] = o;
}

// ---------------------------------------------------------------------------
extern "C" void kernel_launch(void* const* d_in, const int* in_sizes, int n_in,
                              void* d_out, int out_size, void* d_ws, size_t ws_size,
                              hipStream_t stream) {
    const float* t1 = (const float*)d_in[0];
    const float* t2 = (const float*)d_in[1];
    const float* W  = (const float*)d_in[2];
    float* out = (float*)d_out;

    char* ws = (char*)d_ws;
    float*    Gp  = (float*)ws;                               // NKC*NTOK*NEXP f (8 MB)
    float*    Cp  = Gp + (size_t)NKC * NTOK * NEXP;           // NKC*NTOK f
    float*    nrm = Cp + (size_t)NKC * NTOK;                  // NEXP f
    _Float16* Whg = (_Float16*)(nrm + NEXP);                  // NEXP*KTOT halves (256 KB)
    _Float16* Wlg = Whg + (size_t)NEXP * KTOT;                // NEXP*KTOT halves

    prep_w<<<NEXP, 256, 0, stream>>>(W, Whg, Wlg, nrm);
    gemm_mfma<<<dim3(NTOK / MT, NKC), 256, 0, stream>>>(t1, t2, Whg, Wlg, Gp, Cp);
    finalize<<<NTOK / 4, 256, 0, stream>>>(Gp, Cp, nrm, out);
}